// Round 8
// baseline (116.734 us; speedup 1.0000x reference)
//
#include <hip/hip_runtime.h>
#include <cstddef>
#include <cstdint>

#define NPT 16384   // N
#define NB  4       // B
// C = 64, K = 16, O = 128

typedef float    f32x4 __attribute__((ext_vector_type(4)));
typedef uint32_t u32x4 __attribute__((ext_vector_type(4)));

__device__ __forceinline__ uint32_t bf16_rtne(float f) {
    uint32_t u = __builtin_bit_cast(uint32_t, f);
    return (u + 0x7FFFu + ((u >> 16) & 1u)) >> 16;
}

// ---------------------------------------------------------------------------
// K1: fused 1x1 conv + BN(eps=1e-5) + ReLU for q, k, v.
// q out: [B][N][64] fp32. k,v out PACKED bf16: kv[p][c] = (bf16(k)<<16)|bf16(v)
// -> one 256B row per point; per-batch working set 4 MiB ~ one XCD L2.
// grid (N/64, B), block 256. Register-tiled GEMM, M=192 (q|k|v), tile n=64.
// ---------------------------------------------------------------------------
__global__ __launch_bounds__(256) void k_qkv(
    const float* __restrict__ feat_in,
    const float* __restrict__ Wq, const float* __restrict__ Wk, const float* __restrict__ Wv,
    const float* __restrict__ Qg, const float* __restrict__ Qb, const float* __restrict__ Qm, const float* __restrict__ Qv,
    const float* __restrict__ Kg, const float* __restrict__ Kb, const float* __restrict__ Km, const float* __restrict__ Kv,
    const float* __restrict__ Vg, const float* __restrict__ Vb, const float* __restrict__ Vm, const float* __restrict__ Vv,
    float* __restrict__ qo, uint32_t* __restrict__ kvo)
{
    __shared__ float wt[64][192];   // wt[c][t*64+o] = W_t[o][c]   (48 KiB)
    __shared__ float fs[64][64];    // fs[c][n_local]              (16 KiB)
    const int tid = threadIdx.x;
    const int b   = blockIdx.y;
    const int n0  = blockIdx.x * 64;

    // ---- stage weights transposed (unscaled; BN folded in epilogue) ----
    {
        const int o  = tid >> 2;          // 0..63
        const int cb = (tid & 3) * 16;    // 0,16,32,48
        const float* Ws[3] = {Wq, Wk, Wv};
        #pragma unroll
        for (int t = 0; t < 3; ++t) {
            const float4* src = reinterpret_cast<const float4*>(Ws[t] + o * 64 + cb);
            #pragma unroll
            for (int k4 = 0; k4 < 4; ++k4) {
                float4 w4 = src[k4];
                wt[cb + k4 * 4 + 0][t * 64 + o] = w4.x;
                wt[cb + k4 * 4 + 1][t * 64 + o] = w4.y;
                wt[cb + k4 * 4 + 2][t * 64 + o] = w4.z;
                wt[cb + k4 * 4 + 3][t * 64 + o] = w4.w;
            }
        }
    }
    // ---- stage feature tile: fs[c][n] from feature[b][c][n0+n] ----
    #pragma unroll
    for (int i = 0; i < 16; ++i) {
        int flat = tid + i * 256;       // 4096 elements
        int c = flat >> 6, n = flat & 63;
        fs[c][n] = feat_in[((size_t)b * 64 + c) * NPT + n0 + n];
    }
    __syncthreads();

    const int to = tid & 15;   // o-quad
    const int tn = tid >> 4;   // n-quad
    float acc[3][4][4];
    #pragma unroll
    for (int t = 0; t < 3; ++t)
        #pragma unroll
        for (int i = 0; i < 4; ++i)
            #pragma unroll
            for (int j = 0; j < 4; ++j) acc[t][i][j] = 0.f;

    #pragma unroll 4
    for (int c = 0; c < 64; ++c) {
        float4 f4  = *reinterpret_cast<const float4*>(&fs[c][tn * 4]);
        float4 wq4 = *reinterpret_cast<const float4*>(&wt[c][to * 4]);
        float4 wk4 = *reinterpret_cast<const float4*>(&wt[c][64 + to * 4]);
        float4 wv4 = *reinterpret_cast<const float4*>(&wt[c][128 + to * 4]);
        float fr[4]    = {f4.x, f4.y, f4.z, f4.w};
        float wr[3][4] = {{wq4.x, wq4.y, wq4.z, wq4.w},
                          {wk4.x, wk4.y, wk4.z, wk4.w},
                          {wv4.x, wv4.y, wv4.z, wv4.w}};
        #pragma unroll
        for (int t = 0; t < 3; ++t)
            #pragma unroll
            for (int oi = 0; oi < 4; ++oi)
                #pragma unroll
                for (int nn = 0; nn < 4; ++nn)
                    acc[t][oi][nn] = fmaf(wr[t][oi], fr[nn], acc[t][oi][nn]);
    }

    // ---- epilogue: BN fold + ReLU; pack k,v -> bf16x2 ----
    float scq[4], shq[4], sck[4], shk[4], scv[4], shv[4];
    #pragma unroll
    for (int oi = 0; oi < 4; ++oi) {
        int o = to * 4 + oi;
        float s;
        s = Qg[o] * rsqrtf(Qv[o] + 1e-5f); scq[oi] = s; shq[oi] = Qb[o] - Qm[o] * s;
        s = Kg[o] * rsqrtf(Kv[o] + 1e-5f); sck[oi] = s; shk[oi] = Kb[o] - Km[o] * s;
        s = Vg[o] * rsqrtf(Vv[o] + 1e-5f); scv[oi] = s; shv[oi] = Vb[o] - Vm[o] * s;
    }
    #pragma unroll
    for (int nn = 0; nn < 4; ++nn) {
        const size_t pidx = (size_t)b * NPT + n0 + tn * 4 + nn;
        // q: [p][c] fp32
        float4 rq;
        rq.x = fmaxf(fmaf(acc[0][0][nn], scq[0], shq[0]), 0.f);
        rq.y = fmaxf(fmaf(acc[0][1][nn], scq[1], shq[1]), 0.f);
        rq.z = fmaxf(fmaf(acc[0][2][nn], scq[2], shq[2]), 0.f);
        rq.w = fmaxf(fmaf(acc[0][3][nn], scq[3], shq[3]), 0.f);
        *reinterpret_cast<float4*>(qo + (pidx << 6) + to * 4) = rq;
        // kv packed: hi16 = k, lo16 = v (keep DEFAULT caching: reused by K2)
        u32x4 pk;
        #pragma unroll
        for (int oi = 0; oi < 4; ++oi) {
            float rk = fmaxf(fmaf(acc[1][oi][nn], sck[oi], shk[oi]), 0.f);
            float rv = fmaxf(fmaf(acc[2][oi][nn], scv[oi], shv[oi]), 0.f);
            pk[oi] = (bf16_rtne(rk) << 16) | bf16_rtne(rv);
        }
        *reinterpret_cast<u32x4*>(kvo + (pidx << 6) + to * 4) = pk;
    }
}

// ---------------------------------------------------------------------------
// K2: gather + attention + weighted sum. One wave per point, lane = channel.
// SMALL-BARRIER variant: 2 points / 128-thread block (2 waves). LDS 9.2 KiB
// -> 16 blocks/CU = 32 waves (100% theoretical occupancy); each __syncthreads
// stalls only 2 waves, and 16 independent blocks per CU fill the gaps
// (barrier-convoy fix for the ~900cyc x-load latency).
// x coalescing preserved: per-channel row = 2pts*16 = 128B = one full line;
// one wave instruction covers 8 whole lines. LDS row stride 36 = 4 (mod 32),
// the same conflict-free b128 pattern as the measured stride-68 layout.
// Writes feat back over q IN PLACE (each address touched by exactly one lane).
// ---------------------------------------------------------------------------
__global__ __launch_bounds__(128) void k_attn(
    const float*    __restrict__ xinfo,
    const int*      __restrict__ nidx,
    float*                       qfeat,   // q in, feat out (aliased on purpose)
    const uint32_t* __restrict__ kv)
{
    __shared__ float xs[64][36];   // [c][pt*16+j], pad 4   (9.2 KiB)
    const int tid  = threadIdx.x;
    const int lane = tid & 63;
    const int wv   = tid >> 6;                // 0..1
    const int p0   = blockIdx.x * 2;
    const int b    = p0 >> 14;
    const int n0   = p0 & 16383;
    const int p    = p0 + wv;

    // ---- neighbor indices via SCALAR path (p is wave-uniform) ----
    const int pu = __builtin_amdgcn_readfirstlane(p);
    const int4* irow = reinterpret_cast<const int4*>(nidx + ((size_t)pu << 4));
    int4 i0 = irow[0], i1 = irow[1], i2 = irow[2], i3 = irow[3];
    const int idxs[16] = {i0.x, i0.y, i0.z, i0.w,  i1.x, i1.y, i1.z, i1.w,
                          i2.x, i2.y, i2.z, i2.w,  i3.x, i3.y, i3.z, i3.w};

    // ---- gathers first: 16 independent loads, SGPR base + lane*4 ----
    uint32_t gr[16];
    #pragma unroll
    for (int j = 0; j < 16; ++j)
        gr[j] = kv[(((size_t)((b << 14) | idxs[j])) << 6) + lane];

    float qc = __builtin_nontemporal_load(qfeat + ((size_t)p << 6) + lane);

    // ---- cooperative x_info tile load (nt): 2048 floats = 4 f32x4/thread ----
    // per channel: 32 consecutive floats (2 points x 16) = 128B = 1 line
    const float* xbase = xinfo + (((size_t)b * 64) * NPT + n0) * 16;
    f32x4 xr[4];
    #pragma unroll
    for (int i = 0; i < 4; ++i) {
        int f = tid + i * 128;        // float4 index in tile, 0..511
        int c = f >> 3, s = f & 7;    // channel, 16B-segment within 128B row
        xr[i] = __builtin_nontemporal_load(
            reinterpret_cast<const f32x4*>(xbase + (size_t)c * (NPT * 16) + s * 4));
    }
    #pragma unroll
    for (int i = 0; i < 4; ++i) {
        int f = tid + i * 128;
        int c = f >> 3, s = f & 7;
        *reinterpret_cast<f32x4*>(&xs[c][s * 4]) = xr[i];
    }

    // unpack gathers while LDS writes drain
    float kgv[16], vgv[16];
    #pragma unroll
    for (int j = 0; j < 16; ++j) {
        kgv[j] = __builtin_bit_cast(float, gr[j] & 0xFFFF0000u);
        vgv[j] = __builtin_bit_cast(float, gr[j] << 16);
    }
    __syncthreads();

    // ---- softmax over K=16, fully in-lane ----
    float w[16];
    #pragma unroll
    for (int k4 = 0; k4 < 4; ++k4) {
        float4 x4 = *reinterpret_cast<const float4*>(&xs[lane][wv * 16 + k4 * 4]);
        w[k4 * 4 + 0] = x4.x * (kgv[k4 * 4 + 0] - qc);
        w[k4 * 4 + 1] = x4.y * (kgv[k4 * 4 + 1] - qc);
        w[k4 * 4 + 2] = x4.z * (kgv[k4 * 4 + 2] - qc);
        w[k4 * 4 + 3] = x4.w * (kgv[k4 * 4 + 3] - qc);
    }

    float mx = w[0];
    #pragma unroll
    for (int j = 1; j < 16; ++j) mx = fmaxf(mx, w[j]);

    float es = 0.f, fsum = 0.f;
    #pragma unroll
    for (int j = 0; j < 16; ++j) {
        float e = __expf(w[j] - mx);
        es += e;
        fsum = fmaf(e, vgv[j], fsum);
    }

    qfeat[((size_t)p << 6) + lane] = fsum / es;   // feat, in place over q
}

// ---------------------------------------------------------------------------
// K3: mlp2 = 1x1 conv (O=128) + BN(eps=1e-6) + LeakyReLU(0.2).  (r5 config)
// grid (N/64, B), block 256. Tile 128o x 64n; wt & feat transposed into LDS.
// Output [B][128][N]; float4 NT stores (256B per 16-lane segment).
// ---------------------------------------------------------------------------
__global__ __launch_bounds__(256) void k_mlp2(
    const float* __restrict__ feat,
    const float* __restrict__ m2w,
    const float* __restrict__ g2, const float* __restrict__ b2,
    const float* __restrict__ m2, const float* __restrict__ v2,
    float* __restrict__ out)
{
    __shared__ float wt [64][132];  // wt[c][o], padded (33 KiB)
    __shared__ float fsh[64][68];   // fsh[c][n], padded (17 KiB)
    const int tid = threadIdx.x;
    const int b   = blockIdx.y;
    const int n0  = blockIdx.x * 64;

    // ---- stage wt[c][o] from m2w[o][c] ----
    {
        const int o  = tid >> 1;          // 0..127
        const int ch = (tid & 1) * 32;    // 0 or 32
        const float4* src = reinterpret_cast<const float4*>(m2w + o * 64 + ch);
        #pragma unroll
        for (int k4 = 0; k4 < 8; ++k4) {
            float4 w4 = src[k4];
            wt[ch + k4 * 4 + 0][o] = w4.x;
            wt[ch + k4 * 4 + 1][o] = w4.y;
            wt[ch + k4 * 4 + 2][o] = w4.z;
            wt[ch + k4 * 4 + 3][o] = w4.w;
        }
    }
    // ---- stage fsh[c][n] from feat[b][n0+n][c] ----
    {
        const int c4 = tid & 15;       // float4 index along c
        const int nl = tid >> 4;       // 0..15
        #pragma unroll
        for (int i = 0; i < 4; ++i) {
            int n = nl + i * 16;
            float4 f4 = *reinterpret_cast<const float4*>(
                feat + (((size_t)b * NPT + n0 + n) << 6) + c4 * 4);
            fsh[c4 * 4 + 0][n] = f4.x;
            fsh[c4 * 4 + 1][n] = f4.y;
            fsh[c4 * 4 + 2][n] = f4.z;
            fsh[c4 * 4 + 3][n] = f4.w;
        }
    }
    __syncthreads();

    const int tn = tid & 15;   // lane's n-quad: n = tn*4 .. tn*4+3 (float4 stores)
    const int to = tid >> 4;   // 0..15 -> o quads {to*4..+3} and {64+to*4..+3}
    float acc[2][4][4];        // [half][oi][ni]
    #pragma unroll
    for (int h = 0; h < 2; ++h)
        #pragma unroll
        for (int i = 0; i < 4; ++i)
            #pragma unroll
            for (int j = 0; j < 4; ++j) acc[h][i][j] = 0.f;

    #pragma unroll 4
    for (int c = 0; c < 64; ++c) {
        float4 wa = *reinterpret_cast<const float4*>(&wt[c][to * 4]);
        float4 wb = *reinterpret_cast<const float4*>(&wt[c][64 + to * 4]);
        float4 f4 = *reinterpret_cast<const float4*>(&fsh[c][tn * 4]);
        float wra[4] = {wa.x, wa.y, wa.z, wa.w};
        float wrb[4] = {wb.x, wb.y, wb.z, wb.w};
        float fr[4]  = {f4.x, f4.y, f4.z, f4.w};
        #pragma unroll
        for (int oi = 0; oi < 4; ++oi)
            #pragma unroll
            for (int ni = 0; ni < 4; ++ni) {
                acc[0][oi][ni] = fmaf(wra[oi], fr[ni], acc[0][oi][ni]);
                acc[1][oi][ni] = fmaf(wrb[oi], fr[ni], acc[1][oi][ni]);
            }
    }

    #pragma unroll
    for (int h = 0; h < 2; ++h)
        #pragma unroll
        for (int oi = 0; oi < 4; ++oi) {
            int o = h * 64 + to * 4 + oi;
            float s  = g2[o] * rsqrtf(v2[o] + 1e-6f);
            float sh = b2[o] - m2[o] * s;
            f32x4 r;
            #pragma unroll
            for (int ni = 0; ni < 4; ++ni) {
                float y = fmaf(acc[h][oi][ni], s, sh);
                r[ni] = (y >= 0.f) ? y : 0.2f * y;
            }
            __builtin_nontemporal_store(r, reinterpret_cast<f32x4*>(
                out + (((size_t)b << 7) + o) * NPT + n0 + tn * 4));
        }
}

// ---------------------------------------------------------------------------
extern "C" void kernel_launch(void* const* d_in, const int* in_sizes, int n_in,
                              void* d_out, int out_size, void* d_ws, size_t ws_size,
                              hipStream_t stream)
{
    const float* xinfo   = (const float*)d_in[0];
    const float* feature = (const float*)d_in[1];
    const int*   nidx    = (const int*)  d_in[2];
    const float* Wq = (const float*)d_in[3];
    const float* Qg = (const float*)d_in[4];
    const float* Qb = (const float*)d_in[5];
    const float* Qm = (const float*)d_in[6];
    const float* Qv = (const float*)d_in[7];
    const float* Wk = (const float*)d_in[8];
    const float* Kg = (const float*)d_in[9];
    const float* Kb = (const float*)d_in[10];
    const float* Km = (const float*)d_in[11];
    const float* Kv = (const float*)d_in[12];
    const float* Wv = (const float*)d_in[13];
    const float* Vg = (const float*)d_in[14];
    const float* Vb = (const float*)d_in[15];
    const float* Vm = (const float*)d_in[16];
    const float* Vv = (const float*)d_in[17];
    const float* m2w = (const float*)d_in[18];
    const float* g2  = (const float*)d_in[19];
    const float* b2  = (const float*)d_in[20];
    const float* m2  = (const float*)d_in[21];
    const float* v2  = (const float*)d_in[22];
    float* out = (float*)d_out;

    // workspace: q/feat (in-place) 16 MiB fp32, packed kv 16 MiB u32
    float*    ws    = (float*)d_ws;
    float*    qf    = ws;
    uint32_t* kvbuf = (uint32_t*)(ws + (size_t)NB * NPT * 64);

    k_qkv<<<dim3(NPT / 64, NB), 256, 0, stream>>>(
        feature, Wq, Wk, Wv,
        Qg, Qb, Qm, Qv, Kg, Kb, Km, Kv, Vg, Vb, Vm, Vv,
        qf, kvbuf);

    k_attn<<<(NB * NPT) / 2, 128, 0, stream>>>(xinfo, nidx, qf, kvbuf);

    k_mlp2<<<dim3(NPT / 64, NB), 256, 0, stream>>>(qf, m2w, g2, b2, m2, v2, out);
}

// Round 9
// 110.813 us; speedup vs baseline: 1.0534x; 1.0534x over previous
//
#include <hip/hip_runtime.h>
#include <cstddef>
#include <cstdint>

#define NPT 16384   // N
#define NB  4       // B
// C = 64, K = 16, O = 128

typedef float    f32x4 __attribute__((ext_vector_type(4)));
typedef uint32_t u32x4 __attribute__((ext_vector_type(4)));
typedef uint16_t u16x4 __attribute__((ext_vector_type(4)));

__device__ __forceinline__ uint32_t bf16_rtne(float f) {
    uint32_t u = __builtin_bit_cast(uint32_t, f);
    return (u + 0x7FFFu + ((u >> 16) & 1u)) >> 16;
}
__device__ __forceinline__ float bf16_hi(uint32_t w) {   // high 16 bits
    return __builtin_bit_cast(float, w & 0xFFFF0000u);
}
__device__ __forceinline__ float bf16_lo(uint32_t w) {   // low 16 bits
    return __builtin_bit_cast(float, w << 16);
}

// ---------------------------------------------------------------------------
// K1: fused 1x1 conv + BN(eps=1e-5) + ReLU for q, k, v.
// q out: [B][N][64] bf16 (u16). k,v out PACKED bf16: kv[p][c]=(k<<16)|v (u32).
// grid (N/64, B), block 256. Register-tiled GEMM, M=192 (q|k|v), tile n=64.
// ---------------------------------------------------------------------------
__global__ __launch_bounds__(256) void k_qkv(
    const float* __restrict__ feat_in,
    const float* __restrict__ Wq, const float* __restrict__ Wk, const float* __restrict__ Wv,
    const float* __restrict__ Qg, const float* __restrict__ Qb, const float* __restrict__ Qm, const float* __restrict__ Qv,
    const float* __restrict__ Kg, const float* __restrict__ Kb, const float* __restrict__ Km, const float* __restrict__ Kv,
    const float* __restrict__ Vg, const float* __restrict__ Vb, const float* __restrict__ Vm, const float* __restrict__ Vv,
    uint16_t* __restrict__ qo, uint32_t* __restrict__ kvo)
{
    __shared__ float wt[64][192];   // wt[c][t*64+o] = W_t[o][c]   (48 KiB)
    __shared__ float fs[64][64];    // fs[c][n_local]              (16 KiB)
    const int tid = threadIdx.x;
    const int b   = blockIdx.y;
    const int n0  = blockIdx.x * 64;

    // ---- stage weights transposed (unscaled; BN folded in epilogue) ----
    {
        const int o  = tid >> 2;          // 0..63
        const int cb = (tid & 3) * 16;    // 0,16,32,48
        const float* Ws[3] = {Wq, Wk, Wv};
        #pragma unroll
        for (int t = 0; t < 3; ++t) {
            const float4* src = reinterpret_cast<const float4*>(Ws[t] + o * 64 + cb);
            #pragma unroll
            for (int k4 = 0; k4 < 4; ++k4) {
                float4 w4 = src[k4];
                wt[cb + k4 * 4 + 0][t * 64 + o] = w4.x;
                wt[cb + k4 * 4 + 1][t * 64 + o] = w4.y;
                wt[cb + k4 * 4 + 2][t * 64 + o] = w4.z;
                wt[cb + k4 * 4 + 3][t * 64 + o] = w4.w;
            }
        }
    }
    // ---- stage feature tile: fs[c][n] from feature[b][c][n0+n] ----
    #pragma unroll
    for (int i = 0; i < 16; ++i) {
        int flat = tid + i * 256;       // 4096 elements
        int c = flat >> 6, n = flat & 63;
        fs[c][n] = feat_in[((size_t)b * 64 + c) * NPT + n0 + n];
    }
    __syncthreads();

    const int to = tid & 15;   // o-quad
    const int tn = tid >> 4;   // n-quad
    float acc[3][4][4];
    #pragma unroll
    for (int t = 0; t < 3; ++t)
        #pragma unroll
        for (int i = 0; i < 4; ++i)
            #pragma unroll
            for (int j = 0; j < 4; ++j) acc[t][i][j] = 0.f;

    #pragma unroll 4
    for (int c = 0; c < 64; ++c) {
        float4 f4  = *reinterpret_cast<const float4*>(&fs[c][tn * 4]);
        float4 wq4 = *reinterpret_cast<const float4*>(&wt[c][to * 4]);
        float4 wk4 = *reinterpret_cast<const float4*>(&wt[c][64 + to * 4]);
        float4 wv4 = *reinterpret_cast<const float4*>(&wt[c][128 + to * 4]);
        float fr[4]    = {f4.x, f4.y, f4.z, f4.w};
        float wr[3][4] = {{wq4.x, wq4.y, wq4.z, wq4.w},
                          {wk4.x, wk4.y, wk4.z, wk4.w},
                          {wv4.x, wv4.y, wv4.z, wv4.w}};
        #pragma unroll
        for (int t = 0; t < 3; ++t)
            #pragma unroll
            for (int oi = 0; oi < 4; ++oi)
                #pragma unroll
                for (int nn = 0; nn < 4; ++nn)
                    acc[t][oi][nn] = fmaf(wr[t][oi], fr[nn], acc[t][oi][nn]);
    }

    // ---- epilogue: BN fold + ReLU; q -> bf16, k,v -> packed bf16x2 ----
    float scq[4], shq[4], sck[4], shk[4], scv[4], shv[4];
    #pragma unroll
    for (int oi = 0; oi < 4; ++oi) {
        int o = to * 4 + oi;
        float s;
        s = Qg[o] * rsqrtf(Qv[o] + 1e-5f); scq[oi] = s; shq[oi] = Qb[o] - Qm[o] * s;
        s = Kg[o] * rsqrtf(Kv[o] + 1e-5f); sck[oi] = s; shk[oi] = Kb[o] - Km[o] * s;
        s = Vg[o] * rsqrtf(Vv[o] + 1e-5f); scv[oi] = s; shv[oi] = Vb[o] - Vm[o] * s;
    }
    #pragma unroll
    for (int nn = 0; nn < 4; ++nn) {
        const size_t pidx = (size_t)b * NPT + n0 + tn * 4 + nn;
        u16x4 rq;
        u32x4 pk;
        #pragma unroll
        for (int oi = 0; oi < 4; ++oi) {
            float q = fmaxf(fmaf(acc[0][oi][nn], scq[oi], shq[oi]), 0.f);
            float rk = fmaxf(fmaf(acc[1][oi][nn], sck[oi], shk[oi]), 0.f);
            float rv = fmaxf(fmaf(acc[2][oi][nn], scv[oi], shv[oi]), 0.f);
            rq[oi] = (uint16_t)bf16_rtne(q);
            pk[oi] = (bf16_rtne(rk) << 16) | bf16_rtne(rv);
        }
        *reinterpret_cast<u16x4*>(qo  + (pidx << 6) + to * 4) = rq;
        *reinterpret_cast<u32x4*>(kvo + (pidx << 6) + to * 4) = pk;
    }
}

// ---------------------------------------------------------------------------
// K2: gather + attention + weighted sum. One wave per point, lane = channel.
// (r5-best config: 4 points / 256-thread block.) Scalar idx path; bf16x2 kv
// gathers (L2-resident); x_info streamed non-temporal through LDS tile.
// q read bf16; feat written bf16 over q IN PLACE. Softmax without max-sub
// (|w| <= ~6, overflow-safe; shorter dependency chain).
// ---------------------------------------------------------------------------
__global__ __launch_bounds__(256) void k_attn(
    const float*    __restrict__ xinfo,
    const int*      __restrict__ nidx,
    uint16_t*                    qfeat,   // q in (bf16), feat out (bf16)
    const uint32_t* __restrict__ kv)
{
    __shared__ float xs[64][68];   // [c][pl*16+j], pad 4 -> <=2-way bank alias
    const int tid  = threadIdx.x;
    const int lane = tid & 63;
    const int wv   = tid >> 6;
    const int p0   = blockIdx.x * 4;
    const int b    = p0 >> 14;
    const int n0   = p0 & 16383;
    const int p    = p0 + wv;

    // ---- neighbor indices via SCALAR path (p is wave-uniform) ----
    const int pu = __builtin_amdgcn_readfirstlane(p);
    const int4* irow = reinterpret_cast<const int4*>(nidx + ((size_t)pu << 4));
    int4 i0 = irow[0], i1 = irow[1], i2 = irow[2], i3 = irow[3];
    const int idxs[16] = {i0.x, i0.y, i0.z, i0.w,  i1.x, i1.y, i1.z, i1.w,
                          i2.x, i2.y, i2.z, i2.w,  i3.x, i3.y, i3.z, i3.w};

    // ---- gathers first: 16 independent loads, SGPR base + lane*4 ----
    uint32_t gr[16];
    #pragma unroll
    for (int j = 0; j < 16; ++j)
        gr[j] = kv[(((size_t)((b << 14) | idxs[j])) << 6) + lane];

    uint16_t qraw = __builtin_nontemporal_load(qfeat + ((size_t)p << 6) + lane);
    float qc = bf16_lo((uint32_t)qraw);

    // ---- cooperative x_info tile load (nt): 4096 floats = 4 x f32x4/thread ----
    const float* xbase = xinfo + (((size_t)b * 64) * NPT + n0) * 16;
    f32x4 xr[4];
    #pragma unroll
    for (int i = 0; i < 4; ++i) {
        int f = tid + i * 256;        // float4 index in tile, 0..1023
        int c = f >> 4, s = f & 15;   // channel, 16B-segment within 256B run
        xr[i] = __builtin_nontemporal_load(
            reinterpret_cast<const f32x4*>(xbase + (size_t)c * (NPT * 16) + s * 4));
    }
    #pragma unroll
    for (int i = 0; i < 4; ++i) {
        int f = tid + i * 256;
        int c = f >> 4, s = f & 15;
        *reinterpret_cast<f32x4*>(&xs[c][s * 4]) = xr[i];
    }
    __syncthreads();

    // ---- softmax over K=16, fully in-lane, no max-sub ----
    float es = 0.f, fsum = 0.f;
    #pragma unroll
    for (int k4 = 0; k4 < 4; ++k4) {
        float4 x4 = *reinterpret_cast<const float4*>(&xs[lane][wv * 16 + k4 * 4]);
        float xv[4] = {x4.x, x4.y, x4.z, x4.w};
        #pragma unroll
        for (int q4 = 0; q4 < 4; ++q4) {
            int j = k4 * 4 + q4;
            float e = __expf(xv[q4] * (bf16_hi(gr[j]) - qc));
            es += e;
            fsum = fmaf(e, bf16_lo(gr[j]), fsum);
        }
    }

    qfeat[((size_t)p << 6) + lane] = (uint16_t)bf16_rtne(fsum / es);
}

// ---------------------------------------------------------------------------
// K3: mlp2 = 1x1 conv (O=128) + BN(eps=1e-6) + LeakyReLU(0.2).  (r5 config)
// feat input is bf16 [p][c]; unpacked to fp32 LDS during staging.
// grid (N/64, B), block 256. Tile 128o x 64n. Output [B][128][N]; float4 NT
// stores (256B per 16-lane segment).
// ---------------------------------------------------------------------------
__global__ __launch_bounds__(256) void k_mlp2(
    const uint16_t* __restrict__ feat,
    const float* __restrict__ m2w,
    const float* __restrict__ g2, const float* __restrict__ b2,
    const float* __restrict__ m2, const float* __restrict__ v2,
    float* __restrict__ out)
{
    __shared__ float wt [64][132];  // wt[c][o], padded (33 KiB)
    __shared__ float fsh[64][69];   // fsh[c][n], pad 5 -> 2-way staging writes
    const int tid = threadIdx.x;
    const int b   = blockIdx.y;
    const int n0  = blockIdx.x * 64;

    // ---- stage wt[c][o] from m2w[o][c] ----
    {
        const int o  = tid >> 1;          // 0..127
        const int ch = (tid & 1) * 32;    // 0 or 32
        const float4* src = reinterpret_cast<const float4*>(m2w + o * 64 + ch);
        #pragma unroll
        for (int k4 = 0; k4 < 8; ++k4) {
            float4 w4 = src[k4];
            wt[ch + k4 * 4 + 0][o] = w4.x;
            wt[ch + k4 * 4 + 1][o] = w4.y;
            wt[ch + k4 * 4 + 2][o] = w4.z;
            wt[ch + k4 * 4 + 3][o] = w4.w;
        }
    }
    // ---- stage fsh[c][n] from bf16 feat[b][n0+n][c] ----
    {
        const int c8 = tid & 7;        // channel-octet: c = c8*8 .. +7
        const int nl = tid >> 3;       // 0..31
        #pragma unroll
        for (int half = 0; half < 2; ++half) {
            int n = nl + half * 32;
            u32x4 rw = *reinterpret_cast<const u32x4*>(
                feat + (((size_t)b * NPT + n0 + n) << 6) + c8 * 8);
            #pragma unroll
            for (int k = 0; k < 4; ++k) {
                uint32_t w2 = rw[k];
                fsh[c8 * 8 + k * 2 + 0][n] = bf16_lo(w2);
                fsh[c8 * 8 + k * 2 + 1][n] = bf16_hi(w2);
            }
        }
    }
    __syncthreads();

    const int tn = tid & 15;   // lane's n-quad: n = tn*4 .. tn*4+3 (float4 stores)
    const int to = tid >> 4;   // 0..15 -> o quads {to*4..+3} and {64+to*4..+3}
    float acc[2][4][4];        // [half][oi][ni]
    #pragma unroll
    for (int h = 0; h < 2; ++h)
        #pragma unroll
        for (int i = 0; i < 4; ++i)
            #pragma unroll
            for (int j = 0; j < 4; ++j) acc[h][i][j] = 0.f;

    #pragma unroll 4
    for (int c = 0; c < 64; ++c) {
        float4 wa = *reinterpret_cast<const float4*>(&wt[c][to * 4]);
        float4 wb = *reinterpret_cast<const float4*>(&wt[c][64 + to * 4]);
        float4 f4 = *reinterpret_cast<const float4*>(&fsh[c][tn * 4]);
        float wra[4] = {wa.x, wa.y, wa.z, wa.w};
        float wrb[4] = {wb.x, wb.y, wb.z, wb.w};
        float fr[4]  = {f4.x, f4.y, f4.z, f4.w};
        #pragma unroll
        for (int oi = 0; oi < 4; ++oi)
            #pragma unroll
            for (int ni = 0; ni < 4; ++ni) {
                acc[0][oi][ni] = fmaf(wra[oi], fr[ni], acc[0][oi][ni]);
                acc[1][oi][ni] = fmaf(wrb[oi], fr[ni], acc[1][oi][ni]);
            }
    }

    #pragma unroll
    for (int h = 0; h < 2; ++h)
        #pragma unroll
        for (int oi = 0; oi < 4; ++oi) {
            int o = h * 64 + to * 4 + oi;
            float s  = g2[o] * rsqrtf(v2[o] + 1e-6f);
            float sh = b2[o] - m2[o] * s;
            f32x4 r;
            #pragma unroll
            for (int ni = 0; ni < 4; ++ni) {
                float y = fmaf(acc[h][oi][ni], s, sh);
                r[ni] = (y >= 0.f) ? y : 0.2f * y;
            }
            __builtin_nontemporal_store(r, reinterpret_cast<f32x4*>(
                out + (((size_t)b << 7) + o) * NPT + n0 + tn * 4));
        }
}

// ---------------------------------------------------------------------------
extern "C" void kernel_launch(void* const* d_in, const int* in_sizes, int n_in,
                              void* d_out, int out_size, void* d_ws, size_t ws_size,
                              hipStream_t stream)
{
    const float* xinfo   = (const float*)d_in[0];
    const float* feature = (const float*)d_in[1];
    const int*   nidx    = (const int*)  d_in[2];
    const float* Wq = (const float*)d_in[3];
    const float* Qg = (const float*)d_in[4];
    const float* Qb = (const float*)d_in[5];
    const float* Qm = (const float*)d_in[6];
    const float* Qv = (const float*)d_in[7];
    const float* Wk = (const float*)d_in[8];
    const float* Kg = (const float*)d_in[9];
    const float* Kb = (const float*)d_in[10];
    const float* Km = (const float*)d_in[11];
    const float* Kv = (const float*)d_in[12];
    const float* Wv = (const float*)d_in[13];
    const float* Vg = (const float*)d_in[14];
    const float* Vb = (const float*)d_in[15];
    const float* Vm = (const float*)d_in[16];
    const float* Vv = (const float*)d_in[17];
    const float* m2w = (const float*)d_in[18];
    const float* g2  = (const float*)d_in[19];
    const float* b2  = (const float*)d_in[20];
    const float* m2  = (const float*)d_in[21];
    const float* v2  = (const float*)d_in[22];
    float* out = (float*)d_out;

    // workspace: q/feat (bf16, in-place) 8 MiB, packed kv 16 MiB
    uint16_t* qf    = (uint16_t*)d_ws;
    uint32_t* kvbuf = (uint32_t*)((uint8_t*)d_ws + (8u << 20));

    k_qkv<<<dim3(NPT / 64, NB), 256, 0, stream>>>(
        feature, Wq, Wk, Wv,
        Qg, Qb, Qm, Qv, Kg, Kb, Km, Kv, Vg, Vb, Vm, Vv,
        qf, kvbuf);

    k_attn<<<(NB * NPT) / 4, 256, 0, stream>>>(xinfo, nidx, qf, kvbuf);

    k_mlp2<<<dim3(NPT / 64, NB), 256, 0, stream>>>(qf, m2w, g2, b2, m2, v2, out);
}